// Round 1
// baseline (564.628 us; speedup 1.0000x reference)
//
#include <hip/hip_runtime.h>
#include <math.h>

#define C_IN  128
#define C_HID 256
#define HGT   64
#define WID   128
#define NBATCH 16
#define HW (HGT * WID)

// ---------------- weight fake-quant (per-tensor symmetric int8) ----------------
__global__ __launch_bounds__(256) void quant4_kernel(
    const float* __restrict__ w0, int n0,
    const float* __restrict__ w1, int n1,
    const float* __restrict__ w2, int n2,
    const float* __restrict__ w3, int n3,
    float* __restrict__ q0, float* __restrict__ q1,
    float* __restrict__ q2, float* __restrict__ q3)
{
    const float* w; float* q; int n;
    switch (blockIdx.x) {
        case 0:  w = w0; q = q0; n = n0; break;
        case 1:  w = w1; q = q1; n = n1; break;
        case 2:  w = w2; q = q2; n = n2; break;
        default: w = w3; q = q3; n = n3; break;
    }
    __shared__ float sm[256];
    int tid = threadIdx.x;
    float m = 0.0f;
    for (int i = tid; i < n; i += 256) m = fmaxf(m, fabsf(w[i]));
    sm[tid] = m;
    __syncthreads();
    for (int s = 128; s > 0; s >>= 1) {
        if (tid < s) sm[tid] = fmaxf(sm[tid], sm[tid + s]);
        __syncthreads();
    }
    float mx = sm[0];
    float scale = mx / 127.0f;
    for (int i = tid; i < n; i += 256) {
        float v = rintf(w[i] / scale);              // round half-to-even, like jnp.round
        v = fminf(fmaxf(v, -128.0f), 127.0f);
        q[i] = v * scale;
    }
}

// ---------------- fused depthwise1 + pointwise1 + ReLU -> h2 ----------------
// One block per (batch, row). 256 threads.
// Phase 1: h1[cin][px] (128x128, LDS) = depthwise 3x3 of x + bias.
// Phase 2: two passes over co-halves of 128; wT[k][co] staged in LDS;
//          each thread computes an 8px x 8co register tile.
__global__ __launch_bounds__(256) void fused_dw1_pw1(
    const float* __restrict__ x,
    const float* __restrict__ qdw1, const float* __restrict__ db1,
    const float* __restrict__ qpw1, const float* __restrict__ pb1,
    float* __restrict__ h2)
{
    __shared__ float h1s[C_IN][WID];   // 64 KB
    __shared__ float wTs[128][132];    // 67.5 KB, pitch 132 (16B-aligned float4 rows)

    const int nb  = blockIdx.x >> 6;   // batch
    const int y   = blockIdx.x & 63;   // row
    const int tid = threadIdx.x;

    const float* xp = x + (size_t)nb * C_IN * HW;

    // ---- phase 1: depthwise conv into LDS ----
    for (int i = 0; i < 64; ++i) {
        int idx = tid + (i << 8);
        int cin = idx >> 7;
        int pxx = idx & 127;
        const float* xc = xp + (size_t)cin * HW;
        const float* wr = qdw1 + cin * 9;
        float acc = db1[cin];
        #pragma unroll
        for (int ky = 0; ky < 3; ++ky) {
            int yy = y + ky - 1;
            if (yy >= 0 && yy < HGT) {
                const float* xr = xc + yy * WID;
                #pragma unroll
                for (int kx = 0; kx < 3; ++kx) {
                    int xx = pxx + kx - 1;
                    float xv = (xx >= 0 && xx < WID) ? xr[xx] : 0.0f;
                    acc += wr[ky * 3 + kx] * xv;
                }
            }
        }
        h1s[cin][pxx] = acc;
    }

    // lane decomposition: 8 co-subblocks x 8 px-subblocks per wave
    const int wave = tid >> 6;
    const int lane = tid & 63;
    const int tx8 = ((wave & 1) << 3) + (lane & 7);   // 0..15  (co block)
    const int ty8 = ((wave >> 1) << 3) + (lane >> 3); // 0..15  (px block)
    const int co0 = tx8 << 3;
    const int px0 = ty8 << 3;

    float acc[8][8];

    for (int half = 0; half < 2; ++half) {
        __syncthreads();  // phase-1 done / previous half's wTs reads done
        // stage wT[k][co] = qpw1[(half*128+co)*128 + k]; coalesced global reads
        for (int i = 0; i < 64; ++i) {
            int idx = tid + (i << 8);
            int k  = idx & 127;
            int co = idx >> 7;
            wTs[k][co] = qpw1[(size_t)((half << 7) + co) * 128 + k];
        }
        __syncthreads();

        #pragma unroll
        for (int i = 0; i < 8; ++i)
            #pragma unroll
            for (int j = 0; j < 8; ++j)
                acc[i][j] = 0.0f;

        for (int k = 0; k < 128; ++k) {
            float4 a0 = *(const float4*)&h1s[k][px0];
            float4 a1 = *(const float4*)&h1s[k][px0 + 4];
            float4 b0 = *(const float4*)&wTs[k][co0];
            float4 b1 = *(const float4*)&wTs[k][co0 + 4];
            float av[8] = {a0.x, a0.y, a0.z, a0.w, a1.x, a1.y, a1.z, a1.w};
            float bv[8] = {b0.x, b0.y, b0.z, b0.w, b1.x, b1.y, b1.z, b1.w};
            #pragma unroll
            for (int i = 0; i < 8; ++i)
                #pragma unroll
                for (int j = 0; j < 8; ++j)
                    acc[i][j] += av[i] * bv[j];
        }

        // epilogue: bias + ReLU, store 8px per co as two float4
        #pragma unroll
        for (int j = 0; j < 8; ++j) {
            int co = (half << 7) + co0 + j;
            float bias = pb1[co];
            float* orow = h2 + (((size_t)nb * C_HID + co) * HGT + y) * WID + px0;
            float4 v0, v1;
            v0.x = fmaxf(acc[0][j] + bias, 0.0f);
            v0.y = fmaxf(acc[1][j] + bias, 0.0f);
            v0.z = fmaxf(acc[2][j] + bias, 0.0f);
            v0.w = fmaxf(acc[3][j] + bias, 0.0f);
            v1.x = fmaxf(acc[4][j] + bias, 0.0f);
            v1.y = fmaxf(acc[5][j] + bias, 0.0f);
            v1.z = fmaxf(acc[6][j] + bias, 0.0f);
            v1.w = fmaxf(acc[7][j] + bias, 0.0f);
            *(float4*)&orow[0] = v0;
            *(float4*)&orow[4] = v1;
        }
    }
}

// ---------------- fused depthwise2 + pointwise2 -> out ----------------
// One block per (batch, row). 256 threads: tid&127 = pixel, tid>>7 = channel half.
__global__ __launch_bounds__(256) void fused_dw2_pw2(
    const float* __restrict__ h2,
    const float* __restrict__ qdw2, const float* __restrict__ db2,
    const float* __restrict__ qpw2, const float* __restrict__ pb2,
    float* __restrict__ out)
{
    const int nb  = blockIdx.x >> 6;
    const int y   = blockIdx.x & 63;
    const int tid = threadIdx.x;
    const int px    = tid & 127;
    const int chalf = tid >> 7;

    const float* h2b = h2 + (size_t)nb * C_HID * HW;
    float acc0 = 0.0f, acc1 = 0.0f;

    for (int ci = 0; ci < 128; ++ci) {
        int ch = (ci << 1) + chalf;
        const float* hc = h2b + (size_t)ch * HW;
        const float* wr = qdw2 + ch * 9;
        float v = db2[ch];
        #pragma unroll
        for (int ky = 0; ky < 3; ++ky) {
            int yy = y + ky - 1;
            if (yy >= 0 && yy < HGT) {
                const float* hr = hc + yy * WID;
                #pragma unroll
                for (int kx = 0; kx < 3; ++kx) {
                    int xx = px + kx - 1;
                    float xv = (xx >= 0 && xx < WID) ? hr[xx] : 0.0f;
                    v += wr[ky * 3 + kx] * xv;
                }
            }
        }
        acc0 += qpw2[ch] * v;
        acc1 += qpw2[C_HID + ch] * v;
    }

    __shared__ float red[2][128];
    if (chalf == 1) { red[0][px] = acc0; red[1][px] = acc1; }
    __syncthreads();
    if (chalf == 0) {
        out[(((size_t)nb * 2 + 0) * HGT + y) * WID + px] = acc0 + red[0][px] + pb2[0];
        out[(((size_t)nb * 2 + 1) * HGT + y) * WID + px] = acc1 + red[1][px] + pb2[1];
    }
}

extern "C" void kernel_launch(void* const* d_in, const int* in_sizes, int n_in,
                              void* d_out, int out_size, void* d_ws, size_t ws_size,
                              hipStream_t stream) {
    const float* x   = (const float*)d_in[0];
    const float* dw1 = (const float*)d_in[1];
    const float* db1 = (const float*)d_in[2];
    const float* pw1 = (const float*)d_in[3];
    const float* pb1 = (const float*)d_in[4];
    const float* dw2 = (const float*)d_in[5];
    const float* db2 = (const float*)d_in[6];
    const float* pw2 = (const float*)d_in[7];
    const float* pb2 = (const float*)d_in[8];
    float* out = (float*)d_out;

    float* ws   = (float*)d_ws;
    float* h2   = ws;                       // 16*256*64*128 = 33,554,432 floats (128 MiB)
    float* qdw1 = ws + (size_t)33554432;    // 1152
    float* qpw1 = qdw1 + 1152;              // 32768
    float* qdw2 = qpw1 + 32768;             // 2304
    float* qpw2 = qdw2 + 2304;              // 512

    quant4_kernel<<<4, 256, 0, stream>>>(
        dw1, C_IN * 9,
        pw1, C_HID * C_IN,
        dw2, C_HID * 9,
        pw2, 2 * C_HID,
        qdw1, qpw1, qdw2, qpw2);

    fused_dw1_pw1<<<NBATCH * HGT, 256, 0, stream>>>(x, qdw1, db1, qpw1, pb1, h2);

    fused_dw2_pw2<<<NBATCH * HGT, 256, 0, stream>>>(h2, qdw2, db2, qpw2, pb2, out);
}

// Round 2
// 304.274 us; speedup vs baseline: 1.8557x; 1.8557x over previous
//
#include <hip/hip_runtime.h>
#include <math.h>

#define C_IN  128
#define C_HID 256
#define HGT   64
#define WID   128
#define NBATCH 16
#define HW (HGT * WID)

typedef unsigned int   uint32;
typedef unsigned short ushort16;

__device__ __forceinline__ float bf2f(ushort16 u) {
    return __uint_as_float(((uint32)u) << 16);
}
__device__ __forceinline__ ushort16 f2bf(float f) {
    uint32 u = __float_as_uint(f);
    u = (u + 0x7fff + ((u >> 16) & 1)) >> 16;   // round-to-nearest-even
    return (ushort16)u;
}

// ---------------- weight fake-quant (per-tensor symmetric int8) ----------------
__global__ __launch_bounds__(256) void quant4_kernel(
    const float* __restrict__ w0, int n0,
    const float* __restrict__ w1, int n1,
    const float* __restrict__ w2, int n2,
    const float* __restrict__ w3, int n3,
    float* __restrict__ q0, float* __restrict__ q1,
    float* __restrict__ q2, float* __restrict__ q3)
{
    const float* w; float* q; int n;
    switch (blockIdx.x) {
        case 0:  w = w0; q = q0; n = n0; break;
        case 1:  w = w1; q = q1; n = n1; break;
        case 2:  w = w2; q = q2; n = n2; break;
        default: w = w3; q = q3; n = n3; break;
    }
    __shared__ float sm[256];
    int tid = threadIdx.x;
    float m = 0.0f;
    for (int i = tid; i < n; i += 256) m = fmaxf(m, fabsf(w[i]));
    sm[tid] = m;
    __syncthreads();
    for (int s = 128; s > 0; s >>= 1) {
        if (tid < s) sm[tid] = fmaxf(sm[tid], sm[tid + s]);
        __syncthreads();
    }
    float scale = sm[0] / 127.0f;
    for (int i = tid; i < n; i += 256) {
        float v = rintf(w[i] / scale);
        v = fminf(fmaxf(v, -128.0f), 127.0f);
        q[i] = v * scale;
    }
}

// ---------------- fused depthwise1 + pointwise1 + ReLU -> h2 (bf16) ----------------
// One block per (batch,row), 512 threads = 8 waves, 24 KB LDS -> 2 blocks/CU.
// K (=cin, 128) is processed in 8 slices of 16:
//   stage wT[16][256] + depthwise h1buf[16][128], barrier, 16 FMA steps.
// Each thread owns an 8px x 8co fp32 register tile (acc accumulates across slices).
__global__ __launch_bounds__(512, 4) void fused_dw1_pw1(
    const float* __restrict__ x,
    const float* __restrict__ qdw1, const float* __restrict__ db1,
    const float* __restrict__ qpw1, const float* __restrict__ pb1,
    ushort16* __restrict__ h2b)
{
    __shared__ float h1buf[16][WID];     // 8 KB
    __shared__ float wTs[16][C_HID];     // 16 KB

    const int nb   = blockIdx.x >> 6;
    const int y    = blockIdx.x & 63;
    const int tid  = threadIdx.x;
    const int wave = tid >> 6;
    const int lane = tid & 63;
    // subtile grid: 32 co-subtiles (4 wave-groups x 8 lanes) x 16 px-subtiles (2 x 8)
    const int co0 = (((wave & 3) << 3) + (lane & 7)) << 3;   // 0..248
    const int px0 = (((wave >> 2) << 3) + (lane >> 3)) << 3; // 0..120

    const float* xb = x + (size_t)nb * C_IN * HW;

    float acc[8][8];
    #pragma unroll
    for (int i = 0; i < 8; ++i)
        #pragma unroll
        for (int j = 0; j < 8; ++j)
            acc[i][j] = 0.0f;

    for (int s = 0; s < 8; ++s) {
        if (s) __syncthreads();   // previous slice's reads done

        // ---- stage pointwise weight slice: wTs[kk][co] = qpw1[co][s*16+kk] ----
        {
            int co  = tid >> 1;            // 0..255
            int kk0 = (tid & 1) << 3;      // 0 or 8
            const float* src = qpw1 + (size_t)co * C_IN + (s << 4) + kk0;
            float4 v0 = *(const float4*)src;
            float4 v1 = *(const float4*)(src + 4);
            wTs[kk0 + 0][co] = v0.x; wTs[kk0 + 1][co] = v0.y;
            wTs[kk0 + 2][co] = v0.z; wTs[kk0 + 3][co] = v0.w;
            wTs[kk0 + 4][co] = v1.x; wTs[kk0 + 5][co] = v1.y;
            wTs[kk0 + 6][co] = v1.z; wTs[kk0 + 7][co] = v1.w;
        }

        // ---- depthwise 3x3 for this cin slice ----
        #pragma unroll
        for (int i = 0; i < 4; ++i) {
            int idx = tid + (i << 9);
            int px  = idx & 127;
            int cl  = idx >> 7;            // 0..15
            int cin = (s << 4) + cl;
            const float* xc = xb + (size_t)cin * HW;
            const float* wr = qdw1 + cin * 9;
            float a = db1[cin];
            #pragma unroll
            for (int ky = 0; ky < 3; ++ky) {
                int yy = y + ky - 1;
                if (yy >= 0 && yy < HGT) {
                    const float* xr = xc + yy * WID;
                    float lft = (px > 0)       ? xr[px - 1] : 0.0f;
                    float mid = xr[px];
                    float rgt = (px < WID - 1) ? xr[px + 1] : 0.0f;
                    a = fmaf(wr[ky * 3 + 0], lft, a);
                    a = fmaf(wr[ky * 3 + 1], mid, a);
                    a = fmaf(wr[ky * 3 + 2], rgt, a);
                }
            }
            h1buf[cl][px] = a;
        }
        __syncthreads();

        // ---- GEMM: 16 K-steps ----
        #pragma unroll 4
        for (int kk = 0; kk < 16; ++kk) {
            float4 a0 = *(const float4*)&h1buf[kk][px0];
            float4 a1 = *(const float4*)&h1buf[kk][px0 + 4];
            float4 b0 = *(const float4*)&wTs[kk][co0];
            float4 b1 = *(const float4*)&wTs[kk][co0 + 4];
            float av[8] = {a0.x, a0.y, a0.z, a0.w, a1.x, a1.y, a1.z, a1.w};
            float bv[8] = {b0.x, b0.y, b0.z, b0.w, b1.x, b1.y, b1.z, b1.w};
            #pragma unroll
            for (int i = 0; i < 8; ++i)
                #pragma unroll
                for (int j = 0; j < 8; ++j)
                    acc[i][j] = fmaf(av[i], bv[j], acc[i][j]);
        }
    }

    // ---- epilogue: bias + ReLU + bf16 pack, 16B store per co ----
    #pragma unroll
    for (int j = 0; j < 8; ++j) {
        int co = co0 + j;
        float bias = pb1[co];
        uint32 w[4];
        #pragma unroll
        for (int p = 0; p < 4; ++p) {
            float v0 = fmaxf(acc[2 * p + 0][j] + bias, 0.0f);
            float v1 = fmaxf(acc[2 * p + 1][j] + bias, 0.0f);
            w[p] = (uint32)f2bf(v0) | ((uint32)f2bf(v1) << 16);
        }
        uint4 vv = make_uint4(w[0], w[1], w[2], w[3]);
        *(uint4*)(h2b + (((size_t)nb * C_HID + co) * HGT + y) * WID + px0) = vv;
    }
}

// ---------------- fused depthwise2 + pointwise2 -> out ----------------
// One block per (batch,row), 512 threads: tid&127 = pixel, tid>>7 = channel group.
__global__ __launch_bounds__(512) void fused_dw2_pw2(
    const ushort16* __restrict__ h2b,
    const float* __restrict__ qdw2, const float* __restrict__ db2,
    const float* __restrict__ qpw2, const float* __restrict__ pb2,
    float* __restrict__ out)
{
    __shared__ float red[3][2][WID];

    const int nb  = blockIdx.x >> 6;
    const int y   = blockIdx.x & 63;
    const int tid = threadIdx.x;
    const int px  = tid & 127;
    const int q   = tid >> 7;     // 0..3, wave-uniform

    const ushort16* hb = h2b + (size_t)nb * C_HID * HW;
    float acc0 = 0.0f, acc1 = 0.0f;

    for (int ci = 0; ci < 64; ++ci) {
        int ch = __builtin_amdgcn_readfirstlane((q << 6) + ci);  // force scalar weight loads
        const ushort16* hc = hb + (size_t)ch * HW + (size_t)y * WID + px;
        const float* wr = qdw2 + ch * 9;
        float v = db2[ch];
        #pragma unroll
        for (int ky = 0; ky < 3; ++ky) {
            int yy = y + ky - 1;
            if (yy >= 0 && yy < HGT) {
                const ushort16* row = hc + (ky - 1) * WID;
                float mid = bf2f(row[0]);
                float lft = (px > 0)       ? bf2f(row[-1]) : 0.0f;
                float rgt = (px < WID - 1) ? bf2f(row[1])  : 0.0f;
                v = fmaf(wr[ky * 3 + 0], lft, v);
                v = fmaf(wr[ky * 3 + 1], mid, v);
                v = fmaf(wr[ky * 3 + 2], rgt, v);
            }
        }
        acc0 = fmaf(qpw2[ch], v, acc0);
        acc1 = fmaf(qpw2[C_HID + ch], v, acc1);
    }

    if (q) { red[q - 1][0][px] = acc0; red[q - 1][1][px] = acc1; }
    __syncthreads();
    if (q == 0) {
        acc0 += red[0][0][px] + red[1][0][px] + red[2][0][px] + pb2[0];
        acc1 += red[0][1][px] + red[1][1][px] + red[2][1][px] + pb2[1];
        out[(((size_t)nb * 2 + 0) * HGT + y) * WID + px] = acc0;
        out[(((size_t)nb * 2 + 1) * HGT + y) * WID + px] = acc1;
    }
}

extern "C" void kernel_launch(void* const* d_in, const int* in_sizes, int n_in,
                              void* d_out, int out_size, void* d_ws, size_t ws_size,
                              hipStream_t stream) {
    const float* x   = (const float*)d_in[0];
    const float* dw1 = (const float*)d_in[1];
    const float* db1 = (const float*)d_in[2];
    const float* pw1 = (const float*)d_in[3];
    const float* pb1 = (const float*)d_in[4];
    const float* dw2 = (const float*)d_in[5];
    const float* db2 = (const float*)d_in[6];
    const float* pw2 = (const float*)d_in[7];
    const float* pb2 = (const float*)d_in[8];
    float* out = (float*)d_out;

    ushort16* h2b = (ushort16*)d_ws;                      // 33,554,432 bf16 = 64 MiB
    float* qbase = (float*)((char*)d_ws + (size_t)33554432 * 2);
    float* qdw1 = qbase;            // 1152
    float* qpw1 = qdw1 + 1152;      // 32768
    float* qdw2 = qpw1 + 32768;     // 2304
    float* qpw2 = qdw2 + 2304;      // 512

    quant4_kernel<<<4, 256, 0, stream>>>(
        dw1, C_IN * 9,
        pw1, C_HID * C_IN,
        dw2, C_HID * 9,
        pw2, 2 * C_HID,
        qdw1, qpw1, qdw2, qpw2);

    fused_dw1_pw1<<<NBATCH * HGT, 512, 0, stream>>>(x, qdw1, db1, qpw1, pb1, h2b);

    fused_dw2_pw2<<<NBATCH * HGT, 512, 0, stream>>>(h2b, qdw2, db2, qpw2, pb2, out);
}

// Round 3
// 197.455 us; speedup vs baseline: 2.8595x; 1.5410x over previous
//
#include <hip/hip_runtime.h>
#include <math.h>

#define C_IN  128
#define C_HID 256
#define HGT   64
#define WID   128
#define NBATCH 16
#define HW (HGT * WID)

typedef unsigned int   uint32;
typedef unsigned short u16;
typedef float f32x4  __attribute__((ext_vector_type(4)));
typedef short bf16x8 __attribute__((ext_vector_type(8)));

__device__ __forceinline__ uint32 f2bf_bits(float f) {
    uint32 u = __float_as_uint(f);
    u = (u + 0x7fff + ((u >> 16) & 1)) >> 16;   // RNE
    return u;
}
__device__ __forceinline__ float bf_lo(uint32 v) { return __uint_as_float(v << 16); }
__device__ __forceinline__ float bf_hi(uint32 v) { return __uint_as_float(v & 0xffff0000u); }

// ============ quant: per-tensor symmetric int8 fake-quant + repack ============
// block 0: dw1 -> qdw1T[9][128] (dequantized fp32, tap-major)
// block 1: pw1 -> Blin (MFMA-fragment-linear bf16 INTEGER values) + scales[0]
// block 2: dw2 -> qdw2T[9][256]
// block 3: pw2 -> qpw2[2][256] (dequantized fp32)
__global__ __launch_bounds__(256) void quant4_kernel(
    const float* __restrict__ dw1, const float* __restrict__ pw1,
    const float* __restrict__ dw2, const float* __restrict__ pw2,
    float* __restrict__ qdw1T, u16* __restrict__ Blin,
    float* __restrict__ qdw2T, float* __restrict__ qpw2,
    float* __restrict__ scales)
{
    const float* w; int n;
    switch (blockIdx.x) {
        case 0:  w = dw1; n = C_IN * 9;    break;
        case 1:  w = pw1; n = C_HID * C_IN; break;
        case 2:  w = dw2; n = C_HID * 9;   break;
        default: w = pw2; n = 2 * C_HID;   break;
    }
    __shared__ float sm[256];
    int tid = threadIdx.x;
    float m = 0.0f;
    for (int i = tid; i < n; i += 256) m = fmaxf(m, fabsf(w[i]));
    sm[tid] = m;
    __syncthreads();
    for (int s = 128; s > 0; s >>= 1) {
        if (tid < s) sm[tid] = fmaxf(sm[tid], sm[tid + s]);
        __syncthreads();
    }
    const float scale = sm[0] / 127.0f;

    if (blockIdx.x == 0) {
        for (int i = tid; i < C_IN * 9; i += 256) {
            int t = i >> 7, cin = i & 127;
            float v = rintf(dw1[cin * 9 + t] / scale);
            v = fminf(fmaxf(v, -128.0f), 127.0f);
            qdw1T[i] = v * scale;
        }
    } else if (blockIdx.x == 1) {
        if (tid == 0) scales[0] = scale;
        // slot s = (kstep*16 + cofrag)*64 + lane; each slot = 8 bf16 (16B)
        for (int i = tid; i < 4096; i += 256) {
            int kstep = i >> 10;
            int cf    = (i >> 6) & 15;
            int l     = i & 63;
            int co    = cf * 16 + (l & 15);
            int k0    = kstep * 32 + ((l >> 4) << 3);
            const float* src = pw1 + (size_t)co * C_IN + k0;
            f32x4 a = *(const f32x4*)src;
            f32x4 b = *(const f32x4*)(src + 4);
            float vv[8] = {a.x, a.y, a.z, a.w, b.x, b.y, b.z, b.w};
            uint32 pk[4];
            #pragma unroll
            for (int p = 0; p < 4; ++p) {
                float v0 = fminf(fmaxf(rintf(vv[2 * p]     / scale), -128.0f), 127.0f);
                float v1 = fminf(fmaxf(rintf(vv[2 * p + 1] / scale), -128.0f), 127.0f);
                pk[p] = f2bf_bits(v0) | (f2bf_bits(v1) << 16);   // ints exact in bf16
            }
            ((uint4*)Blin)[i] = make_uint4(pk[0], pk[1], pk[2], pk[3]);
        }
    } else if (blockIdx.x == 2) {
        for (int i = tid; i < C_HID * 9; i += 256) {
            int t = i >> 8, ch = i & 255;
            float v = rintf(dw2[ch * 9 + t] / scale);
            v = fminf(fmaxf(v, -128.0f), 127.0f);
            qdw2T[i] = v * scale;
        }
    } else {
        for (int i = tid; i < 2 * C_HID; i += 256) {
            float v = rintf(pw2[i] / scale);
            v = fminf(fmaxf(v, -128.0f), 127.0f);
            qpw2[i] = v * scale;
        }
    }
}

// ============ fused depthwise1 + MFMA pointwise1 + ReLU -> h2 (bf16) ============
// One block per (batch,row), 512 threads = 8 waves.
// Phase 1 (VALU): dw 3x3 -> h1s[128px][128k] bf16 in LDS (pitch 136).
// Phase 2 (MFMA): C[128px][256co] via 16x16x32 bf16; B = integer-valued bf16
//                 fragments from Blin (global, L2-resident); acc * scale at end.
__global__ __launch_bounds__(512, 4) void fused_dw1_pw1(
    const float* __restrict__ x,
    const float* __restrict__ qdw1T, const float* __restrict__ db1,
    const u16* __restrict__ Blin, const float* __restrict__ pb1,
    const float* __restrict__ scales,
    u16* __restrict__ h2b)
{
    __shared__ __align__(16) u16 h1s[128][136];   // 34816 B

    const int bid = blockIdx.x;
    const int swz = (bid & 7) * 128 + (bid >> 3);   // XCD-bijective
    const int nb  = swz >> 6;
    const int y   = swz & 63;
    const int tid = threadIdx.x;

    // ---------- phase 1: depthwise ----------
    {
        const int q = tid & 31, g = tid >> 5;     // px0 = 4q, cin0 = 8g
        const int px0 = q << 2, cin0 = g << 3;

        f32x4 bia = *(const f32x4*)(db1 + cin0);
        f32x4 bib = *(const f32x4*)(db1 + cin0 + 4);
        float a32[8][4];
        #pragma unroll
        for (int c = 0; c < 8; ++c) {
            float b = (c < 4) ? ((const float*)&bia)[c] : ((const float*)&bib)[c - 4];
            #pragma unroll
            for (int p = 0; p < 4; ++p) a32[c][p] = b;
        }

        #pragma unroll
        for (int ky = 0; ky < 3; ++ky) {
            int yy = y + ky - 1;
            if (yy < 0 || yy >= HGT) continue;
            float w3[3][8];
            #pragma unroll
            for (int kx = 0; kx < 3; ++kx) {
                f32x4 wa = *(const f32x4*)(qdw1T + (ky * 3 + kx) * C_IN + cin0);
                f32x4 wb = *(const f32x4*)(qdw1T + (ky * 3 + kx) * C_IN + cin0 + 4);
                w3[kx][0] = wa.x; w3[kx][1] = wa.y; w3[kx][2] = wa.z; w3[kx][3] = wa.w;
                w3[kx][4] = wb.x; w3[kx][5] = wb.y; w3[kx][6] = wb.z; w3[kx][7] = wb.w;
            }
            #pragma unroll
            for (int c = 0; c < 8; ++c) {
                const float* xr = x + (((size_t)nb * C_IN + cin0 + c) * HGT + yy) * WID;
                f32x4 s0 = (q > 0)  ? *(const f32x4*)(xr + px0 - 4) : f32x4{0, 0, 0, 0};
                f32x4 s1 = *(const f32x4*)(xr + px0);
                f32x4 s2 = (q < 31) ? *(const f32x4*)(xr + px0 + 4) : f32x4{0, 0, 0, 0};
                float seg[12] = {s0.x, s0.y, s0.z, s0.w, s1.x, s1.y, s1.z, s1.w,
                                 s2.x, s2.y, s2.z, s2.w};
                #pragma unroll
                for (int kx = 0; kx < 3; ++kx)
                    #pragma unroll
                    for (int p = 0; p < 4; ++p)
                        a32[c][p] = fmaf(w3[kx][c], seg[p + kx + 3], a32[c][p]);
            }
        }

        // pack -> LDS: h1s[px][cin0..cin0+7], one b128 per px
        #pragma unroll
        for (int p = 0; p < 4; ++p) {
            uint32 pk[4];
            #pragma unroll
            for (int i = 0; i < 4; ++i)
                pk[i] = f2bf_bits(a32[2 * i][p]) | (f2bf_bits(a32[2 * i + 1][p]) << 16);
            *(uint4*)&h1s[px0 + p][cin0] = make_uint4(pk[0], pk[1], pk[2], pk[3]);
        }
    }
    __syncthreads();

    // ---------- phase 2: MFMA GEMM ----------
    const int wave = tid >> 6, lane = tid & 63;
    const int l15 = lane & 15, l4 = lane >> 4;
    const int wco = wave >> 2;          // 0..1: co half (128 each)
    const int wpx = wave & 3;           // 0..3: 32-px quarter
    const int px0w = wpx << 5;
    const float bscale = scales[0];

    f32x4 acc[2][8];
    #pragma unroll
    for (int f = 0; f < 2; ++f)
        #pragma unroll
        for (int c = 0; c < 8; ++c) acc[f][c] = f32x4{0, 0, 0, 0};

    const bf16x8* BL = (const bf16x8*)Blin;

    #pragma unroll
    for (int ks = 0; ks < 4; ++ks) {
        bf16x8 bfrag[8];
        #pragma unroll
        for (int c = 0; c < 8; ++c)
            bfrag[c] = BL[(ks * 16 + wco * 8 + c) * 64 + lane];
        bf16x8 afrag[2];
        #pragma unroll
        for (int f = 0; f < 2; ++f)
            afrag[f] = *(const bf16x8*)&h1s[px0w + f * 16 + l15][ks * 32 + l4 * 8];
        #pragma unroll
        for (int f = 0; f < 2; ++f)
            #pragma unroll
            for (int c = 0; c < 8; ++c)
                acc[f][c] = __builtin_amdgcn_mfma_f32_16x16x32_bf16(
                    afrag[f], bfrag[c], acc[f][c], 0, 0, 0);
    }

    // epilogue: scale + bias + ReLU, bf16 pack, 8B stores
    #pragma unroll
    for (int f = 0; f < 2; ++f) {
        int pxb = px0w + f * 16 + l4 * 4;
        #pragma unroll
        for (int c = 0; c < 8; ++c) {
            int co = wco * 128 + c * 16 + l15;
            float bias = pb1[co];
            float v0 = fmaxf(fmaf(acc[f][c].x, bscale, bias), 0.0f);
            float v1 = fmaxf(fmaf(acc[f][c].y, bscale, bias), 0.0f);
            float v2 = fmaxf(fmaf(acc[f][c].z, bscale, bias), 0.0f);
            float v3 = fmaxf(fmaf(acc[f][c].w, bscale, bias), 0.0f);
            uint2 pk;
            pk.x = f2bf_bits(v0) | (f2bf_bits(v1) << 16);
            pk.y = f2bf_bits(v2) | (f2bf_bits(v3) << 16);
            *(uint2*)(h2b + (((size_t)nb * C_HID + co) * HGT + y) * WID + pxb) = pk;
        }
    }
}

// ============ fused depthwise2 + pointwise2 -> out ============
// One block per (batch,row), 512 threads: q=tid&31 (4 px), g=tid>>5 (16 ch).
__global__ __launch_bounds__(512, 4) void fused_dw2_pw2(
    const u16* __restrict__ h2b,
    const float* __restrict__ qdw2T, const float* __restrict__ db2,
    const float* __restrict__ qpw2, const float* __restrict__ pb2,
    float* __restrict__ out)
{
    __shared__ float red[16][2][WID];   // 16 KB

    const int bid = blockIdx.x;
    const int swz = (bid & 7) * 128 + (bid >> 3);
    const int nb  = swz >> 6;
    const int y   = swz & 63;
    const int tid = threadIdx.x;
    const int q = tid & 31, g = tid >> 5;
    const int px0 = q << 2;

    float o0[4] = {0, 0, 0, 0}, o1[4] = {0, 0, 0, 0};

    #pragma unroll
    for (int cb = 0; cb < 2; ++cb) {
        const int ch0 = (g << 4) + (cb << 3);

        f32x4 bia = *(const f32x4*)(db2 + ch0);
        f32x4 bib = *(const f32x4*)(db2 + ch0 + 4);
        float a32[8][4];
        #pragma unroll
        for (int c = 0; c < 8; ++c) {
            float b = (c < 4) ? ((const float*)&bia)[c] : ((const float*)&bib)[c - 4];
            #pragma unroll
            for (int p = 0; p < 4; ++p) a32[c][p] = b;
        }

        #pragma unroll
        for (int ky = 0; ky < 3; ++ky) {
            int yy = y + ky - 1;
            if (yy < 0 || yy >= HGT) continue;
            float w3[3][8];
            #pragma unroll
            for (int kx = 0; kx < 3; ++kx) {
                f32x4 wa = *(const f32x4*)(qdw2T + (ky * 3 + kx) * C_HID + ch0);
                f32x4 wb = *(const f32x4*)(qdw2T + (ky * 3 + kx) * C_HID + ch0 + 4);
                w3[kx][0] = wa.x; w3[kx][1] = wa.y; w3[kx][2] = wa.z; w3[kx][3] = wa.w;
                w3[kx][4] = wb.x; w3[kx][5] = wb.y; w3[kx][6] = wb.z; w3[kx][7] = wb.w;
            }
            #pragma unroll
            for (int c = 0; c < 8; ++c) {
                const u16* hr = h2b + (((size_t)nb * C_HID + ch0 + c) * HGT + yy) * WID;
                uint32 lft = (q > 0)  ? *(const uint32*)(hr + px0 - 2) : 0u;
                uint2  mid = *(const uint2*)(hr + px0);
                uint32 rgt = (q < 31) ? *(const uint32*)(hr + px0 + 4) : 0u;
                float em1 = bf_hi(lft);
                float e0 = bf_lo(mid.x), e1 = bf_hi(mid.x);
                float e2 = bf_lo(mid.y), e3 = bf_hi(mid.y);
                float e4 = bf_lo(rgt);
                float seg[6] = {em1, e0, e1, e2, e3, e4};
                #pragma unroll
                for (int kx = 0; kx < 3; ++kx)
                    #pragma unroll
                    for (int p = 0; p < 4; ++p)
                        a32[c][p] = fmaf(w3[kx][c], seg[p + kx], a32[c][p]);
            }
        }

        // pointwise-2 accumulate
        f32x4 wa0 = *(const f32x4*)(qpw2 + ch0);
        f32x4 wa1 = *(const f32x4*)(qpw2 + ch0 + 4);
        f32x4 wb0 = *(const f32x4*)(qpw2 + C_HID + ch0);
        f32x4 wb1 = *(const f32x4*)(qpw2 + C_HID + ch0 + 4);
        float wA[8] = {wa0.x, wa0.y, wa0.z, wa0.w, wa1.x, wa1.y, wa1.z, wa1.w};
        float wB[8] = {wb0.x, wb0.y, wb0.z, wb0.w, wb1.x, wb1.y, wb1.z, wb1.w};
        #pragma unroll
        for (int c = 0; c < 8; ++c)
            #pragma unroll
            for (int p = 0; p < 4; ++p) {
                o0[p] = fmaf(wA[c], a32[c][p], o0[p]);
                o1[p] = fmaf(wB[c], a32[c][p], o1[p]);
            }
    }

    *(f32x4*)&red[g][0][px0] = f32x4{o0[0], o0[1], o0[2], o0[3]};
    *(f32x4*)&red[g][1][px0] = f32x4{o1[0], o1[1], o1[2], o1[3]};
    __syncthreads();

    if (tid < 256) {
        int px = tid & 127;
        int o  = tid >> 7;
        float s = pb2[o];
        #pragma unroll
        for (int gg = 0; gg < 16; ++gg) s += red[gg][o][px];
        out[(((size_t)nb * 2 + o) * HGT + y) * WID + px] = s;
    }
}

extern "C" void kernel_launch(void* const* d_in, const int* in_sizes, int n_in,
                              void* d_out, int out_size, void* d_ws, size_t ws_size,
                              hipStream_t stream) {
    const float* x   = (const float*)d_in[0];
    const float* dw1 = (const float*)d_in[1];
    const float* db1 = (const float*)d_in[2];
    const float* pw1 = (const float*)d_in[3];
    const float* pb1 = (const float*)d_in[4];
    const float* dw2 = (const float*)d_in[5];
    const float* db2 = (const float*)d_in[6];
    const float* pw2 = (const float*)d_in[7];
    const float* pb2 = (const float*)d_in[8];
    float* out = (float*)d_out;

    char* wsb = (char*)d_ws;
    u16*   h2bf   = (u16*)wsb;                               // 64 MiB
    u16*   Blin   = (u16*)(wsb + (size_t)67108864);          // 64 KiB
    float* qdw1T  = (float*)(wsb + 67108864 + 65536);        // 4608 B
    float* qdw2T  = (float*)(wsb + 67108864 + 65536 + 4608); // 9216 B
    float* qpw2   = (float*)(wsb + 67108864 + 65536 + 4608 + 9216);   // 2048 B
    float* scales = (float*)(wsb + 67108864 + 65536 + 4608 + 9216 + 2048);

    quant4_kernel<<<4, 256, 0, stream>>>(dw1, pw1, dw2, pw2,
                                         qdw1T, Blin, qdw2T, qpw2, scales);

    fused_dw1_pw1<<<NBATCH * HGT, 512, 0, stream>>>(
        x, qdw1T, db1, Blin, pb1, scales, h2bf);

    fused_dw2_pw2<<<NBATCH * HGT, 512, 0, stream>>>(
        h2bf, qdw2T, db2, qpw2, pb2, out);
}

// Round 4
// 123.291 us; speedup vs baseline: 4.5796x; 1.6015x over previous
//
#include <hip/hip_runtime.h>
#include <math.h>

#define C_IN  128
#define C_HID 256
#define HGT   64
#define WID   128
#define NBATCH 16
#define HW (HGT * WID)

typedef unsigned int   uint32;
typedef unsigned short u16;
typedef float f32x4  __attribute__((ext_vector_type(4)));
typedef short bf16x8 __attribute__((ext_vector_type(8)));

__device__ __forceinline__ uint32 f2bf_bits(float f) {
    uint32 u = __float_as_uint(f);
    u = (u + 0x7fff + ((u >> 16) & 1)) >> 16;   // RNE
    return u;
}
__device__ __forceinline__ float bf_lo(uint32 v) { return __uint_as_float(v << 16); }
__device__ __forceinline__ float bf_hi(uint32 v) { return __uint_as_float(v & 0xffff0000u); }
__device__ __forceinline__ float bf_u16(u16 v)   { return __uint_as_float(((uint32)v) << 16); }

// ============ quant: per-tensor symmetric int8 fake-quant + repack ============
__global__ __launch_bounds__(256) void quant4_kernel(
    const float* __restrict__ dw1, const float* __restrict__ pw1,
    const float* __restrict__ dw2, const float* __restrict__ pw2,
    float* __restrict__ qdw1T, u16* __restrict__ Blin,
    float* __restrict__ qdw2T, float* __restrict__ qpw2,
    float* __restrict__ scales)
{
    const float* w; int n;
    switch (blockIdx.x) {
        case 0:  w = dw1; n = C_IN * 9;    break;
        case 1:  w = pw1; n = C_HID * C_IN; break;
        case 2:  w = dw2; n = C_HID * 9;   break;
        default: w = pw2; n = 2 * C_HID;   break;
    }
    __shared__ float sm[256];
    int tid = threadIdx.x;
    float m = 0.0f;
    for (int i = tid; i < n; i += 256) m = fmaxf(m, fabsf(w[i]));
    sm[tid] = m;
    __syncthreads();
    for (int s = 128; s > 0; s >>= 1) {
        if (tid < s) sm[tid] = fmaxf(sm[tid], sm[tid + s]);
        __syncthreads();
    }
    const float scale = sm[0] / 127.0f;

    if (blockIdx.x == 0) {
        for (int i = tid; i < C_IN * 9; i += 256) {
            int t = i >> 7, cin = i & 127;
            float v = rintf(dw1[cin * 9 + t] / scale);
            v = fminf(fmaxf(v, -128.0f), 127.0f);
            qdw1T[i] = v * scale;
        }
    } else if (blockIdx.x == 1) {
        if (tid == 0) scales[0] = scale;
        // slot s = (kstep*16 + cofrag)*64 + lane; each slot = 8 bf16 (16B)
        for (int i = tid; i < 4096; i += 256) {
            int kstep = i >> 10;
            int cf    = (i >> 6) & 15;
            int l     = i & 63;
            int co    = cf * 16 + (l & 15);
            int k0    = kstep * 32 + ((l >> 4) << 3);
            const float* src = pw1 + (size_t)co * C_IN + k0;
            f32x4 a = *(const f32x4*)src;
            f32x4 b = *(const f32x4*)(src + 4);
            float vv[8] = {a.x, a.y, a.z, a.w, b.x, b.y, b.z, b.w};
            uint32 pk[4];
            #pragma unroll
            for (int p = 0; p < 4; ++p) {
                float v0 = fminf(fmaxf(rintf(vv[2 * p]     / scale), -128.0f), 127.0f);
                float v1 = fminf(fmaxf(rintf(vv[2 * p + 1] / scale), -128.0f), 127.0f);
                pk[p] = f2bf_bits(v0) | (f2bf_bits(v1) << 16);   // ints exact in bf16
            }
            ((uint4*)Blin)[i] = make_uint4(pk[0], pk[1], pk[2], pk[3]);
        }
    } else if (blockIdx.x == 2) {
        for (int i = tid; i < C_HID * 9; i += 256) {
            int t = i >> 8, ch = i & 255;
            float v = rintf(dw2[ch * 9 + t] / scale);
            v = fminf(fmaxf(v, -128.0f), 127.0f);
            qdw2T[i] = v * scale;
        }
    } else {
        for (int i = tid; i < 2 * C_HID; i += 256) {
            float v = rintf(pw2[i] / scale);
            v = fminf(fmaxf(v, -128.0f), 127.0f);
            qpw2[i] = v * scale;
        }
    }
}

// ============ fused depthwise1 + MFMA pointwise1 + ReLU -> h2 bf16 [nb][y][ch][px] ============
// One block per (batch,row), 512 threads = 8 waves.
__global__ __launch_bounds__(512, 4) void fused_dw1_pw1(
    const float* __restrict__ x,
    const float* __restrict__ qdw1T, const float* __restrict__ db1,
    const u16* __restrict__ Blin, const float* __restrict__ pb1,
    const float* __restrict__ scales,
    u16* __restrict__ h2b)
{
    __shared__ __align__(16) u16 h1s[128][136];   // 34816 B; reused for C staging

    const int bid = blockIdx.x;
    const int swz = (bid & 7) * 128 + (bid >> 3);   // XCD-bijective
    const int nb  = swz >> 6;
    const int y   = swz & 63;
    const int tid = threadIdx.x;

    // ---------- phase 1: depthwise (hoisted load batches for MLP) ----------
    {
        const int q = tid & 31, g = tid >> 5;
        const int px0 = q << 2, cin0 = g << 3;

        f32x4 bia = *(const f32x4*)(db1 + cin0);
        f32x4 bib = *(const f32x4*)(db1 + cin0 + 4);
        float a32[8][4];
        #pragma unroll
        for (int c = 0; c < 8; ++c) {
            float b = (c < 4) ? ((const float*)&bia)[c] : ((const float*)&bib)[c - 4];
            #pragma unroll
            for (int p = 0; p < 4; ++p) a32[c][p] = b;
        }

        #pragma unroll
        for (int ky = 0; ky < 3; ++ky) {
            int yy = y + ky - 1;
            if (yy < 0 || yy >= HGT) continue;
            const float* xbase = x + (((size_t)nb * C_IN + cin0) * HGT + yy) * WID;

            // hoisted independent loads: 8 x 16B mid + 16 x 4B edges in flight
            f32x4 mid[8]; float lf[8], rt[8];
            #pragma unroll
            for (int c = 0; c < 8; ++c) {
                const float* xr = xbase + (size_t)c * HW;
                mid[c] = *(const f32x4*)(xr + px0);
                lf[c]  = (q > 0)  ? xr[px0 - 1] : 0.0f;
                rt[c]  = (q < 31) ? xr[px0 + 4] : 0.0f;
            }

            float w3[3][8];
            #pragma unroll
            for (int kx = 0; kx < 3; ++kx) {
                f32x4 wa = *(const f32x4*)(qdw1T + (ky * 3 + kx) * C_IN + cin0);
                f32x4 wb = *(const f32x4*)(qdw1T + (ky * 3 + kx) * C_IN + cin0 + 4);
                w3[kx][0] = wa.x; w3[kx][1] = wa.y; w3[kx][2] = wa.z; w3[kx][3] = wa.w;
                w3[kx][4] = wb.x; w3[kx][5] = wb.y; w3[kx][6] = wb.z; w3[kx][7] = wb.w;
            }

            #pragma unroll
            for (int c = 0; c < 8; ++c) {
                float seg[6] = {lf[c], mid[c].x, mid[c].y, mid[c].z, mid[c].w, rt[c]};
                #pragma unroll
                for (int kx = 0; kx < 3; ++kx)
                    #pragma unroll
                    for (int p = 0; p < 4; ++p)
                        a32[c][p] = fmaf(w3[kx][c], seg[p + kx], a32[c][p]);
            }
        }

        // pack -> LDS: h1s[px][cin0..cin0+7]
        #pragma unroll
        for (int p = 0; p < 4; ++p) {
            uint32 pk[4];
            #pragma unroll
            for (int i = 0; i < 4; ++i)
                pk[i] = f2bf_bits(a32[2 * i][p]) | (f2bf_bits(a32[2 * i + 1][p]) << 16);
            *(uint4*)&h1s[px0 + p][cin0] = make_uint4(pk[0], pk[1], pk[2], pk[3]);
        }
    }
    __syncthreads();

    // ---------- phase 2: MFMA GEMM ----------
    const int wave = tid >> 6, lane = tid & 63;
    const int l15 = lane & 15, l4 = lane >> 4;
    const int wco = wave >> 2;          // 0..1: co half
    const int wpx = wave & 3;           // 0..3: 32-px quarter
    const int px0w = wpx << 5;
    const float bscale = scales[0];

    f32x4 acc[2][8];
    #pragma unroll
    for (int f = 0; f < 2; ++f)
        #pragma unroll
        for (int c = 0; c < 8; ++c) acc[f][c] = f32x4{0, 0, 0, 0};

    const bf16x8* BL = (const bf16x8*)Blin;

    #pragma unroll
    for (int ks = 0; ks < 4; ++ks) {
        bf16x8 bfrag[8];
        #pragma unroll
        for (int c = 0; c < 8; ++c)
            bfrag[c] = BL[(ks * 16 + wco * 8 + c) * 64 + lane];
        bf16x8 afrag[2];
        #pragma unroll
        for (int f = 0; f < 2; ++f)
            afrag[f] = *(const bf16x8*)&h1s[px0w + f * 16 + l15][ks * 32 + l4 * 8];
        #pragma unroll
        for (int f = 0; f < 2; ++f)
            #pragma unroll
            for (int c = 0; c < 8; ++c)
                acc[f][c] = __builtin_amdgcn_mfma_f32_16x16x32_bf16(
                    afrag[f], bfrag[c], acc[f][c], 0, 0, 0);
    }

    // epilogue: scale+bias+ReLU in regs, then LDS-staged coalesced stream to h2 slab
    uint2 pk[2][8];
    #pragma unroll
    for (int f = 0; f < 2; ++f)
        #pragma unroll
        for (int c = 0; c < 8; ++c) {
            int co = wco * 128 + c * 16 + l15;
            float bias = pb1[co];
            float v0 = fmaxf(fmaf(acc[f][c].x, bscale, bias), 0.0f);
            float v1 = fmaxf(fmaf(acc[f][c].y, bscale, bias), 0.0f);
            float v2 = fmaxf(fmaf(acc[f][c].z, bscale, bias), 0.0f);
            float v3 = fmaxf(fmaf(acc[f][c].w, bscale, bias), 0.0f);
            pk[f][c].x = f2bf_bits(v0) | (f2bf_bits(v1) << 16);
            pk[f][c].y = f2bf_bits(v2) | (f2bf_bits(v3) << 16);
        }

    u16* slab = h2b + (size_t)(nb * HGT + y) * (C_HID * WID);

    #pragma unroll
    for (int h = 0; h < 2; ++h) {
        __syncthreads();   // h=0: all mfma reads of h1s done; h=1: half-0 stream reads done
        if (wco == h) {
            #pragma unroll
            for (int f = 0; f < 2; ++f)
                #pragma unroll
                for (int c = 0; c < 8; ++c)
                    *(uint2*)&h1s[c * 16 + l15][px0w + f * 16 + l4 * 4] = pk[f][c];
        }
        __syncthreads();
        // stream 32 KB linearly: 512 thr x 4 x 16B, fully coalesced
        #pragma unroll
        for (int i = 0; i < 4; ++i) {
            int gI = tid + (i << 9);           // 0..2047
            int co = gI >> 4;                  // 0..127 within half
            int px = (gI & 15) << 3;
            *(uint4*)(slab + ((h << 7) + co) * WID + px) = *(const uint4*)&h1s[co][px];
        }
    }
}

// ============ fused depthwise2 + pointwise2 -> out ============
// One block per (batch,row), 512 threads: cg=tid>>4 (8 ch), pg=tid&15 (8 px).
__global__ __launch_bounds__(512, 4) void fused_dw2_pw2(
    const u16* __restrict__ h2b,   // [nb][y][ch][px]
    const float* __restrict__ qdw2T, const float* __restrict__ db2,
    const float* __restrict__ qpw2, const float* __restrict__ pb2,
    float* __restrict__ out)
{
    __shared__ float red[32][2][WID];   // 32 KB

    const int bid = blockIdx.x;
    const int swz = (bid & 7) * 128 + (bid >> 3);
    const int nb  = swz >> 6;
    const int y   = swz & 63;
    const int tid = threadIdx.x;
    const int cg = tid >> 4;       // 0..31
    const int pg = tid & 15;       // 0..15
    const int px0 = pg << 3;
    const int ch0 = cg << 3;

    float o0[8] = {0, 0, 0, 0, 0, 0, 0, 0};
    float o1[8] = {0, 0, 0, 0, 0, 0, 0, 0};

    #pragma unroll
    for (int c = 0; c < 8; ++c) {
        const int ch = ch0 + c;
        float v[8];
        float bias = db2[ch];
        #pragma unroll
        for (int p = 0; p < 8; ++p) v[p] = bias;

        #pragma unroll
        for (int ky = 0; ky < 3; ++ky) {
            int yy = y + ky - 1;
            if (yy < 0 || yy >= HGT) continue;
            const u16* row = h2b + (((size_t)(nb * HGT + yy)) * C_HID + ch) * WID;
            uint4 m = *(const uint4*)(row + px0);
            u16 lf = (pg > 0)  ? row[px0 - 1] : (u16)0;
            u16 rt = (pg < 15) ? row[px0 + 8] : (u16)0;
            float seg[10];
            seg[0] = bf_u16(lf);
            seg[1] = bf_lo(m.x); seg[2] = bf_hi(m.x);
            seg[3] = bf_lo(m.y); seg[4] = bf_hi(m.y);
            seg[5] = bf_lo(m.z); seg[6] = bf_hi(m.z);
            seg[7] = bf_lo(m.w); seg[8] = bf_hi(m.w);
            seg[9] = bf_u16(rt);
            float w0 = qdw2T[(ky * 3 + 0) * C_HID + ch];
            float w1 = qdw2T[(ky * 3 + 1) * C_HID + ch];
            float w2 = qdw2T[(ky * 3 + 2) * C_HID + ch];
            #pragma unroll
            for (int p = 0; p < 8; ++p)
                v[p] = fmaf(w0, seg[p], fmaf(w1, seg[p + 1], fmaf(w2, seg[p + 2], v[p])));
        }

        float wa = qpw2[ch], wb = qpw2[C_HID + ch];
        #pragma unroll
        for (int p = 0; p < 8; ++p) {
            o0[p] = fmaf(wa, v[p], o0[p]);
            o1[p] = fmaf(wb, v[p], o1[p]);
        }
    }

    *(f32x4*)&red[cg][0][px0]     = f32x4{o0[0], o0[1], o0[2], o0[3]};
    *(f32x4*)&red[cg][0][px0 + 4] = f32x4{o0[4], o0[5], o0[6], o0[7]};
    *(f32x4*)&red[cg][1][px0]     = f32x4{o1[0], o1[1], o1[2], o1[3]};
    *(f32x4*)&red[cg][1][px0 + 4] = f32x4{o1[4], o1[5], o1[6], o1[7]};
    __syncthreads();

    if (tid < 256) {
        int o  = tid >> 7;
        int px = tid & 127;
        float s = pb2[o];
        #pragma unroll
        for (int g = 0; g < 32; ++g) s += red[g][o][px];
        out[(((size_t)nb * 2 + o) * HGT + y) * WID + px] = s;
    }
}

extern "C" void kernel_launch(void* const* d_in, const int* in_sizes, int n_in,
                              void* d_out, int out_size, void* d_ws, size_t ws_size,
                              hipStream_t stream) {
    const float* x   = (const float*)d_in[0];
    const float* dw1 = (const float*)d_in[1];
    const float* db1 = (const float*)d_in[2];
    const float* pw1 = (const float*)d_in[3];
    const float* pb1 = (const float*)d_in[4];
    const float* dw2 = (const float*)d_in[5];
    const float* db2 = (const float*)d_in[6];
    const float* pw2 = (const float*)d_in[7];
    const float* pb2 = (const float*)d_in[8];
    float* out = (float*)d_out;

    char* wsb = (char*)d_ws;
    u16*   h2bf   = (u16*)wsb;                               // 64 MiB
    u16*   Blin   = (u16*)(wsb + (size_t)67108864);          // 64 KiB
    float* qdw1T  = (float*)(wsb + 67108864 + 65536);        // 4608 B
    float* qdw2T  = (float*)(wsb + 67108864 + 65536 + 4608); // 9216 B
    float* qpw2   = (float*)(wsb + 67108864 + 65536 + 4608 + 9216);   // 2048 B
    float* scales = (float*)(wsb + 67108864 + 65536 + 4608 + 9216 + 2048);

    quant4_kernel<<<4, 256, 0, stream>>>(dw1, pw1, dw2, pw2,
                                         qdw1T, Blin, qdw2T, qpw2, scales);

    fused_dw1_pw1<<<NBATCH * HGT, 512, 0, stream>>>(
        x, qdw1T, db1, Blin, pb1, scales, h2bf);

    fused_dw2_pw2<<<NBATCH * HGT, 512, 0, stream>>>(
        h2bf, qdw2T, db2, qpw2, pb2, out);
}